// Round 23
// baseline (99.830 us; speedup 1.0000x reference)
//
#include <hip/hip_runtime.h>
#include <math.h>

#define TT 1024   // tokens
#define HH 1024   // hidden
#define MM 512    // moe intermediate
#define NE 16     // routed experts (e == NE -> shared expert)
// TOP_K = 2, SCALE = 2.5, NORM_TOPK = true

typedef _Float16 f16;
typedef _Float16 f16x4 __attribute__((ext_vector_type(4)));
typedef _Float16 f16x8 __attribute__((ext_vector_type(8)));
typedef float f32x4 __attribute__((ext_vector_type(4)));

// async global->LDS, 16B/lane, dest = wave-uniform base + lane*16 (linear)
#define GLL(g, l) __builtin_amdgcn_global_load_lds(                         \
    (const __attribute__((address_space(1))) void*)(g),                     \
    (__attribute__((address_space(3))) void*)(l), 16, 0, 0)
#define SB() __builtin_amdgcn_sched_barrier(0)
#define WAITVM(N) { SB(); asm volatile("s_waitcnt vmcnt(" #N ")"); SB(); }
#define BARRIER() __builtin_amdgcn_s_barrier()

// ---------------- pack x -> f16 ----------------
__global__ __launch_bounds__(256) void pack_k(const float* __restrict__ x, f16* __restrict__ xh)
{
    const int i = (blockIdx.x * 256 + threadIdx.x) * 4;
    float4 v = *(const float4*)(x + i);
    f16x4 h = { (f16)v.x, (f16)v.y, (f16)v.z, (f16)v.w };
    *(f16x4*)(xh + i) = h;
}

// ---------------- router ----------------
__global__ __launch_bounds__(256) void router_k(
    const float* __restrict__ x, const float* __restrict__ gate_w,
    int* __restrict__ counts, int* __restrict__ token_list, float* __restrict__ weight_list)
{
    const int wave = threadIdx.x >> 6;
    const int lane = threadIdx.x & 63;
    const int t = (blockIdx.x << 2) + wave;
    const float* xr = x + (size_t)t * HH;
    float xv[16];
#pragma unroll
    for (int i = 0; i < 16; ++i) xv[i] = xr[lane + (i << 6)];
    float sc[NE];
#pragma unroll
    for (int e = 0; e < NE; ++e) {
        const float* gr = gate_w + e * HH;
        float acc = 0.f;
#pragma unroll
        for (int i = 0; i < 16; ++i) acc = fmaf(xv[i], gr[lane + (i << 6)], acc);
#pragma unroll
        for (int off = 32; off > 0; off >>= 1) acc += __shfl_down(acc, off, 64);
        sc[e] = acc;
    }
    if (lane == 0) {
        float l1 = -1e30f, l2 = -1e30f; int i1 = 0, i2 = 0;
#pragma unroll
        for (int e = 0; e < NE; ++e) {
            float v = sc[e];
            if (v > l1) { l2 = l1; i2 = i1; l1 = v; i1 = e; }
            else if (v > l2) { l2 = v; i2 = e; }
        }
        float w1 = 1.f / (1.f + __expf(-l1));
        float w2 = 1.f / (1.f + __expf(-l2));
        const float inv = 2.5f / (w1 + w2 + 1e-20f);
        w1 *= inv; w2 *= inv;
        int s1 = atomicAdd(&counts[i1], 1);
        token_list[i1 * TT + s1] = t;
        weight_list[i1 * TT + s1] = w1;
        int s2 = atomicAdd(&counts[i2], 1);
        token_list[i2 * TT + s2] = t;
        weight_list[i2 * TT + s2] = w2;
    }
}

__global__ void prefix_k(const int* __restrict__ counts, int* __restrict__ offs)
{
    if (threadIdx.x == 0 && blockIdx.x == 0) {
        int acc = 0;
#pragma unroll
        for (int e = 0; e < NE; ++e) { offs[e] = acc; acc += counts[e]; }
        offs[NE] = acc;
    }
}

// ================= fused gate/up (round-16 exact, 41.5 µs) =================
// BM=64, BN=32, BK=64. All K-loop VMEM are GLL. Distance-2 triple-buffer:
// phase T issues tile T+2, vmcnt(12) waits only tile T. A = f16 from xh,
// row-octet swizzle; B = fp32 (r12-verified layout).

#define GU_ISSUE(T2, AS, BG, BU) {                                          \
    _Pragma("unroll") for (int i = 0; i < 2; ++i) {                         \
        GLL(pA[i] + ((T2) << 6), &AS[(w << 4) + (i << 3)][0]);              \
        GLL(pBg[i] + (size_t)((T2) << 6) * MM, &BG[(w << 4) + (i << 3)][0]);\
        GLL(pBu[i] + (size_t)((T2) << 6) * MM, &BU[(w << 4) + (i << 3)][0]); } }

#define GU_COMP(AS, BG, BU) {                                               \
    _Pragma("unroll") for (int h = 0; h < 2; ++h) {                         \
        const int kb = (h << 5) + (lg << 3);                                \
        const int ko = (h << 2) + lg;                                       \
        f16x8 af[2];                                                        \
        _Pragma("unroll") for (int f = 0; f < 2; ++f) {                     \
            const int m = wm + (f << 4) + lm;                               \
            af[f] = *(const f16x8*)&AS[m][(ko ^ (m & 7)) << 3];             \
        }                                                                   \
        const int bc = (wn + lm) ^ ((lg & 1) << 4);                         \
        f16x8 bg, bu;                                                       \
        _Pragma("unroll") for (int j = 0; j < 8; ++j) {                     \
            bg[j] = (f16)BG[kb + j][bc]; bu[j] = (f16)BU[kb + j][bc]; }     \
        _Pragma("unroll") for (int f = 0; f < 2; ++f) {                     \
            accg[f] = __builtin_amdgcn_mfma_f32_16x16x32_f16(af[f], bg, accg[f], 0, 0, 0); \
            accu[f] = __builtin_amdgcn_mfma_f32_16x16x32_f16(af[f], bu, accu[f], 0, 0, 0); } } }

#define GU_PHI(T2, AI, BC, VC) { GU_ISSUE(T2, As##AI, Bg##AI, Bu##AI)       \
    WAITVM(VC) BARRIER();                                                   \
    GU_COMP(As##BC, Bg##BC, Bu##BC) BARRIER(); }
#define GU_PHN(BC, VC) { WAITVM(VC) BARRIER();                              \
    GU_COMP(As##BC, Bg##BC, Bu##BC) BARRIER(); }

__global__ __launch_bounds__(256) void gu_k(
    const f16* __restrict__ xh,
    const float* __restrict__ w_gate, const float* __restrict__ w_up,
    const float* __restrict__ ws_gate, const float* __restrict__ ws_up,
    const int* __restrict__ counts, const int* __restrict__ offs,
    const int* __restrict__ token_list, f16* __restrict__ rinter)
{
    const int F = blockIdx.x;
    const int Q = F & 7;
    const int J = F >> 3;
    int e, tile;
    if (J < 512) { e = Q + ((J >> 8) << 3); tile = J & 255; }
    else         { e = NE; tile = (Q << 5) + (J - 512); }
    const int n0 = (tile & 15) << 5;
    const int r0 = (tile >> 4) << 6;

    int cnt, slot0;
    const float *wgp, *wup;
    if (e < NE) {
        cnt = counts[e]; slot0 = offs[e];
        wgp = w_gate + (size_t)e * HH * MM;
        wup = w_up   + (size_t)e * HH * MM;
    } else {
        cnt = TT; slot0 = 2 * TT;
        wgp = ws_gate; wup = ws_up;
    }
    if (r0 >= cnt) return;

    __shared__ f16  As0[64][64], As1[64][64], As2[64][64];
    __shared__ float Bg0[64][32], Bg1[64][32], Bg2[64][32];
    __shared__ float Bu0[64][32], Bu1[64][32], Bu2[64][32];
    __shared__ int toks[64];

    const int tid = threadIdx.x;
    if (tid < 64) {
        int i = r0 + tid; if (i >= cnt) i = cnt - 1;
        toks[tid] = (e < NE) ? token_list[e * TT + i] : i;
    }
    __syncthreads();

    const int w = tid >> 6, lane = tid & 63;
    const int lm = lane & 15, lg = lane >> 4;
    const int wm = (w >> 1) << 5, wn = (w & 1) << 4;

    // A source (f16): lane>>3 = row-in-group, lane&7 = dest octet slot;
    // source octet = slot ^ (row&7)
    const f16* pA[2];
#pragma unroll
    for (int i = 0; i < 2; ++i) {
        int m = (w << 4) + (i << 3) + (lane >> 3);
        pA[i] = xh + (size_t)toks[m] * HH + (((lane & 7) ^ (lane >> 3)) << 3);
    }
    // B source (fp32, pre-swizzled)
    const float* pBg[2]; const float* pBu[2];
#pragma unroll
    for (int i = 0; i < 2; ++i) {
        int kr = (w << 4) + (i << 3) + (lane >> 3);
        int sg = 4 * ((lane & 7) ^ ((i & 1) << 2));
        pBg[i] = wgp + (size_t)kr * MM + n0 + sg;
        pBu[i] = wup + (size_t)kr * MM + n0 + sg;
    }

    f32x4 accg[2] = {}, accu[2] = {};

    GU_ISSUE(0, As0, Bg0, Bu0)
    GU_ISSUE(1, As1, Bg1, Bu1)

    GU_PHI(2,2,0,12)  GU_PHI(3,0,1,12)  GU_PHI(4,1,2,12)  GU_PHI(5,2,0,12)
    GU_PHI(6,0,1,12)  GU_PHI(7,1,2,12)  GU_PHI(8,2,0,12)  GU_PHI(9,0,1,12)
    GU_PHI(10,1,2,12) GU_PHI(11,2,0,12) GU_PHI(12,0,1,12) GU_PHI(13,1,2,12)
    GU_PHI(14,2,0,12) GU_PHI(15,0,1,12)
    GU_PHN(2,6)       GU_PHN(0,0)

    // epilogue: silu(g)*u -> f16; C/D: col=lane&15, row=(lane>>4)*4+reg
#pragma unroll
    for (int fi = 0; fi < 2; ++fi)
#pragma unroll
        for (int rr = 0; rr < 4; ++rr) {
            const int m = wm + (fi << 4) + (lg << 2) + rr;
            if (r0 + m < cnt) {
                float g = (fi ? accg[1] : accg[0])[rr];
                float u = (fi ? accu[1] : accu[0])[rr];
                float s = g / (1.f + __expf(-g));
                rinter[(size_t)(slot0 + r0 + m) * MM + n0 + wn + lm] = (f16)(s * u);
            }
        }
}

// ================= down (round-22 exact): BM=128, BN=64, BK=32 =================
// 4 waves; wave w owns rows 32w..+31, all 64 cols (2m x 4n frags).
// 4 GLL/wave/phase (2 A + 2 B), dist-2, 3 buffers -> vmcnt(8) steady.

#define DN_ISSUE(T, AS, BS) {                                               \
    GLL(pa0 + ((T) << 5), &AS[w << 5][0]);                                  \
    GLL(pa1 + ((T) << 5), &AS[(w << 5) + 16][0]);                           \
    GLL(pb0 + (size_t)((T) << 5) * HH, &BS[w << 3][0]);                     \
    GLL(pb1 + (size_t)((T) << 5) * HH, &BS[(w << 3) + 4][0]); }

#define DN_COMP(AS, BS) {                                                   \
    f16x8 af[2];                                                            \
    _Pragma("unroll") for (int f = 0; f < 2; ++f) {                         \
        const int m = (w << 5) + (f << 4) + lm;                             \
        af[f] = *(const f16x8*)&AS[m][(lg ^ ((m >> 1) & 3)) << 3];          \
    }                                                                       \
    _Pragma("unroll") for (int nf = 0; nf < 4; ++nf) {                      \
        const int bc = ((nf << 4) + lm) ^ ((lg & 1) << 4);                  \
        f16x8 bv;                                                           \
        _Pragma("unroll") for (int j = 0; j < 8; ++j) bv[j] = (f16)BS[(lg << 3) + j][bc]; \
        _Pragma("unroll") for (int f = 0; f < 2; ++f)                       \
            acc[f][nf] = __builtin_amdgcn_mfma_f32_16x16x32_f16(af[f], bv, acc[f][nf], 0, 0, 0); } }

#define DN_PH(T, CB, IB, VC) {                                              \
    if ((T) + 2 < 16) DN_ISSUE((T) + 2, As##IB, Bs##IB)                     \
    WAITVM(VC) BARRIER();                                                   \
    DN_COMP(As##CB, Bs##CB)                                                 \
    BARRIER(); }

__global__ __launch_bounds__(256) void down_k(
    const f16* __restrict__ rinter,
    const float* __restrict__ w_down, const float* __restrict__ ws_down,
    const int* __restrict__ counts, const int* __restrict__ offs,
    const int* __restrict__ token_list, const float* __restrict__ weight_list,
    float* __restrict__ out)
{
    const int F = blockIdx.x;
    const int Q = F & 7;
    const int J = F >> 3;                // 0..271 per XCD
    int e, n0, r0;
    if (J < 256) {                        // routed: 2 experts x 16n x 8 rowblk
        e = Q + ((J >> 7) << 3);
        const int t = J & 127;
        n0 = (t & 15) << 6;
        r0 = (t >> 4) << 7;
    } else {                              // shared: 16 tiles per XCD
        e = NE;
        const int idx = (Q << 4) + (J - 256);   // 0..127
        n0 = (idx & 15) << 6;
        r0 = (idx >> 4) << 7;
    }

    int cnt, slot0; const float* wdp;
    if (e < NE) { cnt = counts[e]; slot0 = offs[e]; wdp = w_down + (size_t)e * MM * HH; }
    else        { cnt = TT; slot0 = 2 * TT; wdp = ws_down; }
    if (r0 >= cnt) return;

    __shared__ f16  As0[128][32], As1[128][32], As2[128][32];
    __shared__ float Bs0[32][64], Bs1[32][64], Bs2[32][64];

    const int tid = threadIdx.x;
    const int w = tid >> 6, lane = tid & 63;
    const int lm = lane & 15, lg = lane >> 4;

    const int swzA = ((lane & 3) ^ ((lane >> 3) & 3)) << 3;
    int ra = r0 + (w << 5) + (lane >> 2);       if (ra >= cnt) ra = cnt - 1;
    int rb = r0 + (w << 5) + 16 + (lane >> 2);  if (rb >= cnt) rb = cnt - 1;
    const f16* pa0 = rinter + (size_t)(slot0 + ra) * MM + swzA;
    const f16* pa1 = rinter + (size_t)(slot0 + rb) * MM + swzA;
    const int sgd = 4 * ((lane & 15) ^ ((w & 1) << 2));
    const float* pb0 = wdp + (size_t)((w << 3)     + (lane >> 4)) * HH + n0 + sgd;
    const float* pb1 = wdp + (size_t)((w << 3) + 4 + (lane >> 4)) * HH + n0 + sgd;

    f32x4 acc[2][4] = {};

    DN_ISSUE(0, As0, Bs0)
    DN_ISSUE(1, As1, Bs1)

    DN_PH(0,0,2,8)  DN_PH(1,1,0,8)  DN_PH(2,2,1,8)  DN_PH(3,0,2,8)
    DN_PH(4,1,0,8)  DN_PH(5,2,1,8)  DN_PH(6,0,2,8)  DN_PH(7,1,0,8)
    DN_PH(8,2,1,8)  DN_PH(9,0,2,8)  DN_PH(10,1,0,8) DN_PH(11,2,1,8)
    DN_PH(12,0,2,8) DN_PH(13,1,0,8) DN_PH(14,2,1,4) DN_PH(15,0,0,0)

#pragma unroll
    for (int f = 0; f < 2; ++f)
#pragma unroll
        for (int rr = 0; rr < 4; ++rr) {
            const int m = (w << 5) + (f << 4) + (lg << 2) + rr;
            const int row = r0 + m;
            if (row < cnt) {
                int t; float wt;
                if (e < NE) { t = token_list[e * TT + row]; wt = weight_list[e * TT + row]; }
                else        { t = row; wt = 1.f; }
                float* orow = out + (size_t)t * HH + n0;
#pragma unroll
                for (int nf = 0; nf < 4; ++nf)
                    atomicAdd(&orow[(nf << 4) + lm], wt * acc[f][nf][rr]);
            }
        }
}

extern "C" void kernel_launch(void* const* d_in, const int* in_sizes, int n_in,
                              void* d_out, int out_size, void* d_ws, size_t ws_size,
                              hipStream_t stream)
{
    const float* x       = (const float*)d_in[0];
    const float* gate_w  = (const float*)d_in[1];
    const float* w_gate  = (const float*)d_in[2];
    const float* w_up    = (const float*)d_in[3];
    const float* w_down  = (const float*)d_in[4];
    const float* ws_gate = (const float*)d_in[5];
    const float* ws_up   = (const float*)d_in[6];
    const float* ws_down = (const float*)d_in[7];
    float* out = (float*)d_out;

    // ws (r16 layout): counts[16]|offs[17] (64 ints) | token_list 16K ints |
    // weight_list 16K floats | rinter f16 [3072][512] | xh f16 [1024][1024]
    int* counts = (int*)d_ws;
    int* offs = counts + 16;
    int* token_list = counts + 64;
    float* weight_list = (float*)(counts + 64 + NE * TT);
    f16* rinter = (f16*)(counts + 64 + 2 * NE * TT);
    f16* xh = rinter + (size_t)3072 * MM;

    hipMemsetAsync(counts, 0, 64, stream);
    hipMemsetAsync(out, 0, (size_t)TT * HH * sizeof(float), stream);
    pack_k<<<dim3(TT * HH / 1024), 256, 0, stream>>>(x, xh);
    router_k<<<dim3(TT / 4), 256, 0, stream>>>(x, gate_w, counts, token_list, weight_list);
    prefix_k<<<1, 64, 0, stream>>>(counts, offs);
    gu_k<<<dim3(8 * 544), 256, 0, stream>>>(
        xh, w_gate, w_up, ws_gate, ws_up, counts, offs, token_list, rinter);
    down_k<<<dim3(8 * 272), 256, 0, stream>>>(
        rinter, w_down, ws_down, counts, offs, token_list, weight_list, out);
}

// Round 24
// 94.001 us; speedup vs baseline: 1.0620x; 1.0620x over previous
//
#include <hip/hip_runtime.h>
#include <math.h>

#define TT 1024   // tokens
#define HH 1024   // hidden
#define MM 512    // moe intermediate
#define NE 16     // routed experts (e == NE -> shared expert)
// TOP_K = 2, SCALE = 2.5, NORM_TOPK = true

typedef _Float16 f16;
typedef _Float16 f16x4 __attribute__((ext_vector_type(4)));
typedef _Float16 f16x8 __attribute__((ext_vector_type(8)));
typedef float f32x4 __attribute__((ext_vector_type(4)));

// async global->LDS, 16B/lane, dest = wave-uniform base + lane*16 (linear)
#define GLL(g, l) __builtin_amdgcn_global_load_lds(                         \
    (const __attribute__((address_space(1))) void*)(g),                     \
    (__attribute__((address_space(3))) void*)(l), 16, 0, 0)
#define SB() __builtin_amdgcn_sched_barrier(0)
#define WAITVM(N) { SB(); asm volatile("s_waitcnt vmcnt(" #N ")"); SB(); }
#define BARRIER() __builtin_amdgcn_s_barrier()

// ---------------- router (fused x->f16 pack; records top-k slot flag) ----------------
__global__ __launch_bounds__(256) void router_k(
    const float* __restrict__ x, const float* __restrict__ gate_w,
    int* __restrict__ counts, int* __restrict__ token_list,
    float* __restrict__ weight_list, int* __restrict__ flag_list,
    f16* __restrict__ xh)
{
    const int wave = threadIdx.x >> 6;
    const int lane = threadIdx.x & 63;
    const int t = (blockIdx.x << 2) + wave;
    const float* xr = x + (size_t)t * HH;
    float xv[16];
#pragma unroll
    for (int i = 0; i < 16; ++i) xv[i] = xr[lane + (i << 6)];
    // fused pack: each element of x read exactly once here -> store f16
#pragma unroll
    for (int i = 0; i < 16; ++i) xh[(size_t)t * HH + lane + (i << 6)] = (f16)xv[i];
    float sc[NE];
#pragma unroll
    for (int e = 0; e < NE; ++e) {
        const float* gr = gate_w + e * HH;
        float acc = 0.f;
#pragma unroll
        for (int i = 0; i < 16; ++i) acc = fmaf(xv[i], gr[lane + (i << 6)], acc);
#pragma unroll
        for (int off = 32; off > 0; off >>= 1) acc += __shfl_down(acc, off, 64);
        sc[e] = acc;
    }
    if (lane == 0) {
        float l1 = -1e30f, l2 = -1e30f; int i1 = 0, i2 = 0;
#pragma unroll
        for (int e = 0; e < NE; ++e) {
            float v = sc[e];
            if (v > l1) { l2 = l1; i2 = i1; l1 = v; i1 = e; }
            else if (v > l2) { l2 = v; i2 = e; }
        }
        float w1 = 1.f / (1.f + __expf(-l1));
        float w2 = 1.f / (1.f + __expf(-l2));
        const float inv = 2.5f / (w1 + w2 + 1e-20f);
        w1 *= inv; w2 *= inv;
        int s1 = atomicAdd(&counts[i1], 1);
        token_list[i1 * TT + s1] = t;
        weight_list[i1 * TT + s1] = w1;
        flag_list[i1 * TT + s1] = 0;
        int s2 = atomicAdd(&counts[i2], 1);
        token_list[i2 * TT + s2] = t;
        weight_list[i2 * TT + s2] = w2;
        flag_list[i2 * TT + s2] = 1;
    }
}

__global__ void prefix_k(const int* __restrict__ counts, int* __restrict__ offs)
{
    if (threadIdx.x == 0 && blockIdx.x == 0) {
        int acc = 0;
#pragma unroll
        for (int e = 0; e < NE; ++e) { offs[e] = acc; acc += counts[e]; }
        offs[NE] = acc;
    }
}

// ================= fused gate/up (round-16/23 exact) =================
// BM=64, BN=32, BK=64. All K-loop VMEM are GLL. Distance-2 triple-buffer:
// phase T issues tile T+2, vmcnt(12) waits only tile T.

#define GU_ISSUE(T2, AS, BG, BU) {                                          \
    _Pragma("unroll") for (int i = 0; i < 2; ++i) {                         \
        GLL(pA[i] + ((T2) << 6), &AS[(w << 4) + (i << 3)][0]);              \
        GLL(pBg[i] + (size_t)((T2) << 6) * MM, &BG[(w << 4) + (i << 3)][0]);\
        GLL(pBu[i] + (size_t)((T2) << 6) * MM, &BU[(w << 4) + (i << 3)][0]); } }

#define GU_COMP(AS, BG, BU) {                                               \
    _Pragma("unroll") for (int h = 0; h < 2; ++h) {                         \
        const int kb = (h << 5) + (lg << 3);                                \
        const int ko = (h << 2) + lg;                                       \
        f16x8 af[2];                                                        \
        _Pragma("unroll") for (int f = 0; f < 2; ++f) {                     \
            const int m = wm + (f << 4) + lm;                               \
            af[f] = *(const f16x8*)&AS[m][(ko ^ (m & 7)) << 3];             \
        }                                                                   \
        const int bc = (wn + lm) ^ ((lg & 1) << 4);                         \
        f16x8 bg, bu;                                                       \
        _Pragma("unroll") for (int j = 0; j < 8; ++j) {                     \
            bg[j] = (f16)BG[kb + j][bc]; bu[j] = (f16)BU[kb + j][bc]; }     \
        _Pragma("unroll") for (int f = 0; f < 2; ++f) {                     \
            accg[f] = __builtin_amdgcn_mfma_f32_16x16x32_f16(af[f], bg, accg[f], 0, 0, 0); \
            accu[f] = __builtin_amdgcn_mfma_f32_16x16x32_f16(af[f], bu, accu[f], 0, 0, 0); } } }

#define GU_PHI(T2, AI, BC, VC) { GU_ISSUE(T2, As##AI, Bg##AI, Bu##AI)       \
    WAITVM(VC) BARRIER();                                                   \
    GU_COMP(As##BC, Bg##BC, Bu##BC) BARRIER(); }
#define GU_PHN(BC, VC) { WAITVM(VC) BARRIER();                              \
    GU_COMP(As##BC, Bg##BC, Bu##BC) BARRIER(); }

__global__ __launch_bounds__(256) void gu_k(
    const f16* __restrict__ xh,
    const float* __restrict__ w_gate, const float* __restrict__ w_up,
    const float* __restrict__ ws_gate, const float* __restrict__ ws_up,
    const int* __restrict__ counts, const int* __restrict__ offs,
    const int* __restrict__ token_list, f16* __restrict__ rinter)
{
    const int F = blockIdx.x;
    const int Q = F & 7;
    const int J = F >> 3;
    int e, tile;
    if (J < 512) { e = Q + ((J >> 8) << 3); tile = J & 255; }
    else         { e = NE; tile = (Q << 5) + (J - 512); }
    const int n0 = (tile & 15) << 5;
    const int r0 = (tile >> 4) << 6;

    int cnt, slot0;
    const float *wgp, *wup;
    if (e < NE) {
        cnt = counts[e]; slot0 = offs[e];
        wgp = w_gate + (size_t)e * HH * MM;
        wup = w_up   + (size_t)e * HH * MM;
    } else {
        cnt = TT; slot0 = 2 * TT;
        wgp = ws_gate; wup = ws_up;
    }
    if (r0 >= cnt) return;

    __shared__ f16  As0[64][64], As1[64][64], As2[64][64];
    __shared__ float Bg0[64][32], Bg1[64][32], Bg2[64][32];
    __shared__ float Bu0[64][32], Bu1[64][32], Bu2[64][32];
    __shared__ int toks[64];

    const int tid = threadIdx.x;
    if (tid < 64) {
        int i = r0 + tid; if (i >= cnt) i = cnt - 1;
        toks[tid] = (e < NE) ? token_list[e * TT + i] : i;
    }
    __syncthreads();

    const int w = tid >> 6, lane = tid & 63;
    const int lm = lane & 15, lg = lane >> 4;
    const int wm = (w >> 1) << 5, wn = (w & 1) << 4;

    const f16* pA[2];
#pragma unroll
    for (int i = 0; i < 2; ++i) {
        int m = (w << 4) + (i << 3) + (lane >> 3);
        pA[i] = xh + (size_t)toks[m] * HH + (((lane & 7) ^ (lane >> 3)) << 3);
    }
    const float* pBg[2]; const float* pBu[2];
#pragma unroll
    for (int i = 0; i < 2; ++i) {
        int kr = (w << 4) + (i << 3) + (lane >> 3);
        int sg = 4 * ((lane & 7) ^ ((i & 1) << 2));
        pBg[i] = wgp + (size_t)kr * MM + n0 + sg;
        pBu[i] = wup + (size_t)kr * MM + n0 + sg;
    }

    f32x4 accg[2] = {}, accu[2] = {};

    GU_ISSUE(0, As0, Bg0, Bu0)
    GU_ISSUE(1, As1, Bg1, Bu1)

    GU_PHI(2,2,0,12)  GU_PHI(3,0,1,12)  GU_PHI(4,1,2,12)  GU_PHI(5,2,0,12)
    GU_PHI(6,0,1,12)  GU_PHI(7,1,2,12)  GU_PHI(8,2,0,12)  GU_PHI(9,0,1,12)
    GU_PHI(10,1,2,12) GU_PHI(11,2,0,12) GU_PHI(12,0,1,12) GU_PHI(13,1,2,12)
    GU_PHI(14,2,0,12) GU_PHI(15,0,1,12)
    GU_PHN(2,6)       GU_PHN(0,0)

    // epilogue: silu(g)*u -> f16; C/D: col=lane&15, row=(lane>>4)*4+reg
#pragma unroll
    for (int fi = 0; fi < 2; ++fi)
#pragma unroll
        for (int rr = 0; rr < 4; ++rr) {
            const int m = wm + (fi << 4) + (lg << 2) + rr;
            if (r0 + m < cnt) {
                float g = (fi ? accg[1] : accg[0])[rr];
                float u = (fi ? accu[1] : accu[0])[rr];
                float s = g / (1.f + __expf(-g));
                rinter[(size_t)(slot0 + r0 + m) * MM + n0 + wn + lm] = (f16)(s * u);
            }
        }
}

// ================= down (r22 pipeline; plane-store epilogue) =================
// BM=128, BN=64, BK=32. 4 waves; 4 GLL/wave/phase, dist-2, 3 buffers,
// vmcnt(8) steady (12 outstanding, retires tile T). Routed: plain f16 stores
// into plane pR[flag]; shared: direct fp32 store to out (each element once).

#define DN_ISSUE(T, AS, BS) {                                               \
    GLL(pa0 + ((T) << 5), &AS[w << 5][0]);                                  \
    GLL(pa1 + ((T) << 5), &AS[(w << 5) + 16][0]);                           \
    GLL(pb0 + (size_t)((T) << 5) * HH, &BS[w << 3][0]);                     \
    GLL(pb1 + (size_t)((T) << 5) * HH, &BS[(w << 3) + 4][0]); }

#define DN_COMP(AS, BS) {                                                   \
    f16x8 af[2];                                                            \
    _Pragma("unroll") for (int f = 0; f < 2; ++f) {                         \
        const int m = (w << 5) + (f << 4) + lm;                             \
        af[f] = *(const f16x8*)&AS[m][(lg ^ ((m >> 1) & 3)) << 3];          \
    }                                                                       \
    _Pragma("unroll") for (int nf = 0; nf < 4; ++nf) {                      \
        const int bc = ((nf << 4) + lm) ^ ((lg & 1) << 4);                  \
        f16x8 bv;                                                           \
        _Pragma("unroll") for (int j = 0; j < 8; ++j) bv[j] = (f16)BS[(lg << 3) + j][bc]; \
        _Pragma("unroll") for (int f = 0; f < 2; ++f)                       \
            acc[f][nf] = __builtin_amdgcn_mfma_f32_16x16x32_f16(af[f], bv, acc[f][nf], 0, 0, 0); } }

#define DN_PH(T, CB, IB, VC) {                                              \
    if ((T) + 2 < 16) DN_ISSUE((T) + 2, As##IB, Bs##IB)                     \
    WAITVM(VC) BARRIER();                                                   \
    DN_COMP(As##CB, Bs##CB)                                                 \
    BARRIER(); }

__global__ __launch_bounds__(256) void down_k(
    const f16* __restrict__ rinter,
    const float* __restrict__ w_down, const float* __restrict__ ws_down,
    const int* __restrict__ counts, const int* __restrict__ offs,
    const int* __restrict__ token_list, const float* __restrict__ weight_list,
    const int* __restrict__ flag_list,
    f16* __restrict__ pR0, f16* __restrict__ pR1, float* __restrict__ out)
{
    const int F = blockIdx.x;
    const int Q = F & 7;
    const int J = F >> 3;                // 0..271 per XCD
    int e, n0, r0;
    if (J < 256) {                        // routed: 2 experts x 16n x 8 rowblk
        e = Q + ((J >> 7) << 3);
        const int t = J & 127;
        n0 = (t & 15) << 6;
        r0 = (t >> 4) << 7;
    } else {                              // shared: 16 tiles per XCD
        e = NE;
        const int idx = (Q << 4) + (J - 256);   // 0..127
        n0 = (idx & 15) << 6;
        r0 = (idx >> 4) << 7;
    }

    int cnt, slot0; const float* wdp;
    if (e < NE) { cnt = counts[e]; slot0 = offs[e]; wdp = w_down + (size_t)e * MM * HH; }
    else        { cnt = TT; slot0 = 2 * TT; wdp = ws_down; }
    if (r0 >= cnt) return;

    __shared__ f16  As0[128][32], As1[128][32], As2[128][32];
    __shared__ float Bs0[32][64], Bs1[32][64], Bs2[32][64];

    const int tid = threadIdx.x;
    const int w = tid >> 6, lane = tid & 63;
    const int lm = lane & 15, lg = lane >> 4;

    const int swzA = ((lane & 3) ^ ((lane >> 3) & 3)) << 3;
    int ra = r0 + (w << 5) + (lane >> 2);       if (ra >= cnt) ra = cnt - 1;
    int rb = r0 + (w << 5) + 16 + (lane >> 2);  if (rb >= cnt) rb = cnt - 1;
    const f16* pa0 = rinter + (size_t)(slot0 + ra) * MM + swzA;
    const f16* pa1 = rinter + (size_t)(slot0 + rb) * MM + swzA;
    const int sgd = 4 * ((lane & 15) ^ ((w & 1) << 2));
    const float* pb0 = wdp + (size_t)((w << 3)     + (lane >> 4)) * HH + n0 + sgd;
    const float* pb1 = wdp + (size_t)((w << 3) + 4 + (lane >> 4)) * HH + n0 + sgd;

    f32x4 acc[2][4] = {};

    DN_ISSUE(0, As0, Bs0)
    DN_ISSUE(1, As1, Bs1)

    DN_PH(0,0,2,8)  DN_PH(1,1,0,8)  DN_PH(2,2,1,8)  DN_PH(3,0,2,8)
    DN_PH(4,1,0,8)  DN_PH(5,2,1,8)  DN_PH(6,0,2,8)  DN_PH(7,1,0,8)
    DN_PH(8,2,1,8)  DN_PH(9,0,2,8)  DN_PH(10,1,0,8) DN_PH(11,2,1,8)
    DN_PH(12,0,2,8) DN_PH(13,1,0,8) DN_PH(14,2,1,4) DN_PH(15,0,0,0)

#pragma unroll
    for (int f = 0; f < 2; ++f)
#pragma unroll
        for (int rr = 0; rr < 4; ++rr) {
            const int m = (w << 5) + (f << 4) + (lg << 2) + rr;
            const int row = r0 + m;
            if (row < cnt) {
                if (e < NE) {
                    const int t = token_list[e * TT + row];
                    const float wt = weight_list[e * TT + row];
                    f16* orow = (flag_list[e * TT + row] ? pR1 : pR0) + (size_t)t * HH + n0;
#pragma unroll
                    for (int nf = 0; nf < 4; ++nf)
                        orow[(nf << 4) + lm] = (f16)(wt * acc[f][nf][rr]);
                } else {
                    float* orow = out + (size_t)row * HH + n0;
#pragma unroll
                    for (int nf = 0; nf < 4; ++nf)
                        orow[(nf << 4) + lm] = acc[f][nf][rr];
                }
            }
        }
}

// ---------------- reduce: out += pR0 + pR1 ----------------
__global__ __launch_bounds__(256) void reduce_k(
    const f16* __restrict__ pR0, const f16* __restrict__ pR1, float* __restrict__ out)
{
    const int i = (blockIdx.x * 256 + threadIdx.x) * 8;
    f16x8 a = *(const f16x8*)(pR0 + i);
    f16x8 b = *(const f16x8*)(pR1 + i);
    float4 o0 = *(const float4*)(out + i);
    float4 o1 = *(const float4*)(out + i + 4);
    o0.x += (float)a[0] + (float)b[0];
    o0.y += (float)a[1] + (float)b[1];
    o0.z += (float)a[2] + (float)b[2];
    o0.w += (float)a[3] + (float)b[3];
    o1.x += (float)a[4] + (float)b[4];
    o1.y += (float)a[5] + (float)b[5];
    o1.z += (float)a[6] + (float)b[6];
    o1.w += (float)a[7] + (float)b[7];
    *(float4*)(out + i) = o0;
    *(float4*)(out + i + 4) = o1;
}

extern "C" void kernel_launch(void* const* d_in, const int* in_sizes, int n_in,
                              void* d_out, int out_size, void* d_ws, size_t ws_size,
                              hipStream_t stream)
{
    const float* x       = (const float*)d_in[0];
    const float* gate_w  = (const float*)d_in[1];
    const float* w_gate  = (const float*)d_in[2];
    const float* w_up    = (const float*)d_in[3];
    const float* w_down  = (const float*)d_in[4];
    const float* ws_gate = (const float*)d_in[5];
    const float* ws_up   = (const float*)d_in[6];
    const float* ws_down = (const float*)d_in[7];
    float* out = (float*)d_out;

    // ws: counts[16]|offs[17] (64 ints) | token_list NE*TT ints |
    // weight_list NE*TT floats | flag_list NE*TT ints |
    // rinter f16 [3072][512] | xh f16 1M | pR0 f16 1M | pR1 f16 1M  (~9.4 MB)
    int* counts = (int*)d_ws;
    int* offs = counts + 16;
    int* token_list = counts + 64;
    float* weight_list = (float*)(token_list + NE * TT);
    int* flag_list = (int*)(weight_list + NE * TT);
    f16* rinter = (f16*)(flag_list + NE * TT);
    f16* xh = rinter + (size_t)3072 * MM;
    f16* pR0 = xh + (size_t)TT * HH;
    f16* pR1 = pR0 + (size_t)TT * HH;

    hipMemsetAsync(counts, 0, 64, stream);
    router_k<<<dim3(TT / 4), 256, 0, stream>>>(
        x, gate_w, counts, token_list, weight_list, flag_list, xh);
    prefix_k<<<1, 64, 0, stream>>>(counts, offs);
    gu_k<<<dim3(8 * 544), 256, 0, stream>>>(
        xh, w_gate, w_up, ws_gate, ws_up, counts, offs, token_list, rinter);
    down_k<<<dim3(8 * 272), 256, 0, stream>>>(
        rinter, w_down, ws_down, counts, offs, token_list, weight_list, flag_list,
        pR0, pR1, out);
    reduce_k<<<dim3(TT * HH / 2048), 256, 0, stream>>>(pR0, pR1, out);
}